// Round 4
// baseline (385.522 us; speedup 1.0000x reference)
//
#include <hip/hip_runtime.h>
#include <hip/hip_bf16.h>

#define B_      64
#define S_      4096
#define DIM_    256
#define DA_     64
#define NEG_    (-1e30f)
#define CHUNKS_ 16
#define ROWS_   256           // seq rows per chunk (per block)
#define TILES_  4             // 64-row tiles per chunk
#define LDH_    264           // halves per LDS row (256 + 8 pad)
#define PSTR_   258           // partial stride: m, l, acc[256]

typedef _Float16 half8 __attribute__((ext_vector_type(8)));
typedef float float4v __attribute__((ext_vector_type(4)));

// tanh(x) = 1 - 2/(exp(2x)+1); saturates correctly (exp->inf => 1, exp->0 => -1)
static __device__ inline float fast_tanh(float x) {
    float e = __expf(2.0f * x);
    return 1.0f - 2.0f * __builtin_amdgcn_rcpf(e + 1.0f);
}

// Kernel 0: A (DIM x DA fp32) -> fp16 swizzled into exact MFMA B-fragment order,
// and detect mask encoding: flag=1 => int32 elements, flag=0 => 1-byte.
// at_sw index: ((nt*8+kb)*64 + lane)*8 + j  = A[d][kf],
//   d = kb*32 + (lane>>4)*8 + j, kf = nt*16 + (lane&15)
__global__ __launch_bounds__(256) void prep_kernel(
    const float* __restrict__ a, const void* __restrict__ mask,
    _Float16* __restrict__ at_sw, int* __restrict__ flag)
{
    int idx = blockIdx.x * 256 + threadIdx.x;   // 0..16383
    int j    = idx & 7;
    int lane = (idx >> 3) & 63;
    int kbnt = idx >> 9;
    int kb   = kbnt & 7;
    int nt   = kbnt >> 3;
    int d  = kb * 32 + (lane >> 4) * 8 + j;
    int kf = nt * 16 + (lane & 15);
    at_sw[idx] = (_Float16)a[d * DA_ + kf];

    if (blockIdx.x == 0) {
        __shared__ int anynz;
        if (threadIdx.x == 0) anynz = 0;
        __syncthreads();
        const unsigned char* mb = (const unsigned char*)mask;
        int base = threadIdx.x * 4;   // scan first 1024 bytes
        int v = mb[base + 1] | mb[base + 2] | mb[base + 3];
        if (v) atomicOr(&anynz, 1);
        __syncthreads();
        if (threadIdx.x == 0) *flag = (anynz == 0) ? 1 : 0;
    }
}

// Kernel 1: fused logits + masked online-softmax + weighted accumulation.
// One block = (batch b, chunk c of 256 seq rows). Single pass over h.
// Register-prefetched tiles; 3 barriers/tile; per-wave redundant softmax state.
__global__ __launch_bounds__(256) void fused_kernel(
    const float* __restrict__ h, const _Float16* __restrict__ at_sw,
    const float* __restrict__ bvec, const void* __restrict__ mask,
    const int* __restrict__ flag, float* __restrict__ part)
{
    __shared__ _Float16 hf[64 * LDH_];   // 33,792 B
    __shared__ float e_l[64];
    __shared__ float red[4 * 256];       // 4 KiB cross-wave reduce

    const int t = threadIdx.x;
    const int b = blockIdx.x >> 4;
    const int c = blockIdx.x & (CHUNKS_ - 1);
    const int wave = t >> 6;
    const int lane = t & 63;
    const int quad = lane >> 4;
    const int nrow = lane & 15;
    const bool int32enc = (*flag != 0);

    const float* hb = h + ((long long)b * S_ + c * ROWS_) * DIM_;
    float bv[4];
    #pragma unroll
    for (int nt = 0; nt < 4; ++nt) bv[nt] = bvec[nt * 16 + nrow];

    const int dbase = lane * 4;          // 4 consecutive dims owned per thread
    float acc0 = 0.f, acc1 = 0.f, acc2 = 0.f, acc3 = 0.f;
    float m_w = NEG_, l_w = 0.f;         // per-wave (redundant, identical) state

    // prefetch tile 0 into registers
    float4 pf[16];
    #pragma unroll
    for (int j = 0; j < 8; ++j) {
        int f2 = t + j * 256;
        const float* src = hb + (f2 >> 5) * DIM_ + (f2 & 31) * 8;
        pf[2 * j]     = *(const float4*)src;
        pf[2 * j + 1] = *(const float4*)(src + 4);
    }

    for (int tile = 0; tile < TILES_; ++tile) {
        // ---- convert prefetched tile -> fp16 LDS ----
        #pragma unroll
        for (int j = 0; j < 8; ++j) {
            int f2 = t + j * 256;
            int row = f2 >> 5;
            int col = (f2 & 31) * 8;
            float4 v0 = pf[2 * j], v1 = pf[2 * j + 1];
            union { _Float16 hh[8]; uint4 u; } pk;
            pk.hh[0] = (_Float16)v0.x; pk.hh[1] = (_Float16)v0.y;
            pk.hh[2] = (_Float16)v0.z; pk.hh[3] = (_Float16)v0.w;
            pk.hh[4] = (_Float16)v1.x; pk.hh[5] = (_Float16)v1.y;
            pk.hh[6] = (_Float16)v1.z; pk.hh[7] = (_Float16)v1.w;
            *(uint4*)&hf[row * LDH_ + col] = pk.u;
        }
        // ---- issue next tile's loads (in flight across the compute phase) ----
        if (tile + 1 < TILES_) {
            const float* hsrc = hb + (size_t)(tile + 1) * 64 * DIM_;
            #pragma unroll
            for (int j = 0; j < 8; ++j) {
                int f2 = t + j * 256;
                const float* src = hsrc + (f2 >> 5) * DIM_ + (f2 & 31) * 8;
                pf[2 * j]     = *(const float4*)src;
                pf[2 * j + 1] = *(const float4*)(src + 4);
            }
        }
        __syncthreads();

        // ---- MFMA f16: logits for 64 rows (wave w owns rows w*16..+15) ----
        float4v accm[4];
        #pragma unroll
        for (int nt = 0; nt < 4; ++nt) accm[nt] = (float4v){0.f, 0.f, 0.f, 0.f};
        const _Float16* hrow = &hf[(wave * 16 + nrow) * LDH_];
        #pragma unroll
        for (int kb = 0; kb < 8; ++kb) {
            half8 af = *(const half8*)(hrow + kb * 32 + quad * 8);
            #pragma unroll
            for (int nt = 0; nt < 4; ++nt) {
                half8 bf = *(const half8*)(at_sw + ((nt * 8 + kb) * 64 + lane) * 8);
                accm[nt] = __builtin_amdgcn_mfma_f32_16x16x32_f16(af, bf, accm[nt], 0, 0, 0);
            }
        }
        // epilogue: e[m] = sum_n tanh(z)*b[n];  D layout: col=nrow, row=quad*4+r
        #pragma unroll
        for (int r = 0; r < 4; ++r) {
            float p = 0.f;
            #pragma unroll
            for (int nt = 0; nt < 4; ++nt) p += fast_tanh(accm[nt][r]) * bv[nt];
            p += __shfl_xor(p, 1);
            p += __shfl_xor(p, 2);
            p += __shfl_xor(p, 4);
            p += __shfl_xor(p, 8);
            if (nrow == r) e_l[wave * 16 + quad * 4 + r] = p;
        }
        __syncthreads();

        // ---- all-wave redundant masked online-softmax update ----
        long long mi = (long long)b * S_ + c * ROWS_ + tile * 64 + lane;
        int mv = int32enc ? ((const int*)mask)[mi]
                          : (int)((const unsigned char*)mask)[mi];
        float ev = mv ? NEG_ : e_l[lane];
        float mx = ev;
        #pragma unroll
        for (int off = 32; off >= 1; off >>= 1) mx = fmaxf(mx, __shfl_xor(mx, off));
        float m_new = fmaxf(m_w, mx);
        float wv_ = __expf(ev - m_new);          // this lane's weight (s = lane)
        float sm = wv_;
        #pragma unroll
        for (int off = 32; off >= 1; off >>= 1) sm += __shfl_xor(sm, off);
        float rs = __expf(m_w - m_new);
        l_w = l_w * rs + sm;
        m_w = m_new;

        // ---- rescale + accumulate own s-subset (s ≡ wave mod 4) ----
        acc0 *= rs; acc1 *= rs; acc2 *= rs; acc3 *= rs;
        #pragma unroll 4
        for (int i = 0; i < 16; ++i) {
            int s = i * 4 + wave;
            float ws = __shfl(wv_, s);
            union { ushort4 u; _Float16 hh[4]; } pk;
            pk.u = *(const ushort4*)((const unsigned short*)&hf[s * LDH_ + dbase]);
            acc0 = fmaf(ws, (float)pk.hh[0], acc0);
            acc1 = fmaf(ws, (float)pk.hh[1], acc1);
            acc2 = fmaf(ws, (float)pk.hh[2], acc2);
            acc3 = fmaf(ws, (float)pk.hh[3], acc3);
        }
        __syncthreads();   // hf/e_l free for next tile
    }

    // ---- cross-wave reduce + write partial ----
    red[wave * 256 + dbase + 0] = acc0;
    red[wave * 256 + dbase + 1] = acc1;
    red[wave * 256 + dbase + 2] = acc2;
    red[wave * 256 + dbase + 3] = acc3;
    __syncthreads();
    float sum = red[t] + red[256 + t] + red[512 + t] + red[768 + t];
    float* pc = part + (size_t)(b * CHUNKS_ + c) * PSTR_;
    pc[2 + t] = sum;
    if (t == 0) { pc[0] = m_w; pc[1] = l_w; }
}

// Kernel 2: merge per-chunk partials -> out[b][d]
__global__ __launch_bounds__(256) void merge_kernel(
    const float* __restrict__ part, float* __restrict__ out)
{
    const int b = blockIdx.x;
    const int t = threadIdx.x;
    const float* pb = part + (size_t)b * CHUNKS_ * PSTR_;
    float M = NEG_;
    #pragma unroll
    for (int c = 0; c < CHUNKS_; ++c) M = fmaxf(M, pb[c * PSTR_]);
    float L = 0.f, o = 0.f;
    #pragma unroll
    for (int c = 0; c < CHUNKS_; ++c) {
        float sc = __expf(pb[c * PSTR_] - M);
        L += pb[c * PSTR_ + 1] * sc;
        o += pb[c * PSTR_ + 2 + t] * sc;
    }
    out[b * DIM_ + t] = o / L;
}

extern "C" void kernel_launch(void* const* d_in, const int* in_sizes, int n_in,
                              void* d_out, int out_size, void* d_ws, size_t ws_size,
                              hipStream_t stream) {
    const float* h    = (const float*)d_in[0];
    const void*  mask = d_in[1];
    const float* a    = (const float*)d_in[2];
    const float* bvec = (const float*)d_in[3];
    float* out = (float*)d_out;

    char* ws = (char*)d_ws;
    _Float16* at_sw = (_Float16*)ws;              // 32,768 B
    int* flag       = (int*)(ws + 32768);
    float* part     = (float*)(ws + 36864);       // 64*16*258*4 ≈ 1 MiB

    prep_kernel<<<64, 256, 0, stream>>>(a, mask, at_sw, flag);
    fused_kernel<<<B_ * CHUNKS_, 256, 0, stream>>>(h, at_sw, bvec, mask, flag, part);
    merge_kernel<<<B_, 256, 0, stream>>>(part, out);
}

// Round 5
// 377.050 us; speedup vs baseline: 1.0225x; 1.0225x over previous
//
#include <hip/hip_runtime.h>
#include <hip/hip_bf16.h>

#define B_      64
#define S_      4096
#define DIM_    256
#define DA_     64
#define NEG_    (-1e30f)
#define CHUNKS_ 16
#define ROWS_   256           // seq rows per chunk
#define TILES_  4             // 64-row tiles per chunk
#define LDH_    264           // halves per LDS row (256 + 8 pad)
#define PSTR_   258           // partial stride: m, l, acc[256]

typedef _Float16 half8 __attribute__((ext_vector_type(8)));
typedef float float4v __attribute__((ext_vector_type(4)));

// Kernel 0: A (DIM x DA fp32) -> fp16 swizzled into exact MFMA B-fragment order,
// and detect mask encoding: flag=1 => int32 elements, flag=0 => 1-byte.
// at_sw index: ((nt*8+kb)*64 + lane)*8 + j  = A[d][kf],
//   d = kb*32 + (lane>>4)*8 + j, kf = nt*16 + (lane&15)
__global__ __launch_bounds__(256) void prep_kernel(
    const float* __restrict__ a, const void* __restrict__ mask,
    _Float16* __restrict__ at_sw, int* __restrict__ flag)
{
    int idx = blockIdx.x * 256 + threadIdx.x;   // 0..16383
    int j    = idx & 7;
    int lane = (idx >> 3) & 63;
    int kbnt = idx >> 9;
    int kb   = kbnt & 7;
    int nt   = kbnt >> 3;
    int d  = kb * 32 + (lane >> 4) * 8 + j;
    int kf = nt * 16 + (lane & 15);
    at_sw[idx] = (_Float16)a[d * DA_ + kf];

    if (blockIdx.x == 0) {
        __shared__ int anynz;
        if (threadIdx.x == 0) anynz = 0;
        __syncthreads();
        const unsigned char* mb = (const unsigned char*)mask;
        int base = threadIdx.x * 4;   // scan first 1024 bytes
        int v = mb[base + 1] | mb[base + 2] | mb[base + 3];
        if (v) atomicOr(&anynz, 1);
        __syncthreads();
        if (threadIdx.x == 0) *flag = (anynz == 0) ? 1 : 0;
    }
}

// Kernel 1: fused logits + masked online-softmax + weighted accumulation.
// One block = (batch b, chunk c of 256 seq rows). Single pass over h.
// Writes per-chunk partial: [m, l, acc[256]].
// NOTE (R4 post-mortem): register prefetch of the next tile (float4 pf[16] =
// +64 VGPRs) REGRESSED 377->385 us — occupancy drop beats ILP gain here;
// wave-level overlap at full occupancy already hides HBM latency.
__global__ __launch_bounds__(256) void fused_kernel(
    const float* __restrict__ h, const _Float16* __restrict__ at_sw,
    const float* __restrict__ bvec, const void* __restrict__ mask,
    const int* __restrict__ flag, float* __restrict__ part)
{
    __shared__ _Float16 hf[64 * LDH_];   // 33,792 B
    __shared__ float e_l[64];
    __shared__ float w_l[64];
    __shared__ float red[4 * 256];       // 4 KiB (cross-wave acc reduce)
    __shared__ float m_s, l_s, resc_s;

    const int t = threadIdx.x;
    const int b = blockIdx.x >> 4;
    const int c = blockIdx.x & (CHUNKS_ - 1);
    const int wave = t >> 6;
    const int lane = t & 63;
    const int quad = lane >> 4;
    const int nrow = lane & 15;
    const bool int32enc = (*flag != 0);

    if (t == 0) { m_s = NEG_; l_s = 0.f; }

    const float* hb = h + ((long long)b * S_ + c * ROWS_) * DIM_;
    float bv[4];
    #pragma unroll
    for (int nt = 0; nt < 4; ++nt) bv[nt] = bvec[nt * 16 + nrow];

    const int dbase = (t & 63) * 4;   // 4 consecutive dims owned by this thread
    float acc0 = 0.f, acc1 = 0.f, acc2 = 0.f, acc3 = 0.f;

    for (int tile = 0; tile < TILES_; ++tile) {
        // ---- stage 64 rows fp32 -> fp16 LDS ----
        const float* hsrc = hb + (size_t)tile * 64 * DIM_;
        #pragma unroll
        for (int j = 0; j < 8; ++j) {
            int f2 = t + j * 256;            // 8-float chunk id, 0..2047
            int row = f2 >> 5;
            int col = (f2 & 31) * 8;
            const float* src = hsrc + row * DIM_ + col;
            float4 v0 = *(const float4*)(src);
            float4 v1 = *(const float4*)(src + 4);
            union { _Float16 hh[8]; uint4 u; } pk;
            pk.hh[0] = (_Float16)v0.x; pk.hh[1] = (_Float16)v0.y;
            pk.hh[2] = (_Float16)v0.z; pk.hh[3] = (_Float16)v0.w;
            pk.hh[4] = (_Float16)v1.x; pk.hh[5] = (_Float16)v1.y;
            pk.hh[6] = (_Float16)v1.z; pk.hh[7] = (_Float16)v1.w;
            *(uint4*)&hf[row * LDH_ + col] = pk.u;
        }
        __syncthreads();

        // ---- MFMA f16: e for 64 rows (wave w owns rows w*16..w*16+15) ----
        float4v accm[4];
        #pragma unroll
        for (int nt = 0; nt < 4; ++nt) accm[nt] = (float4v){0.f, 0.f, 0.f, 0.f};
        const _Float16* hrow = &hf[(wave * 16 + nrow) * LDH_];
        #pragma unroll
        for (int kb = 0; kb < 8; ++kb) {
            half8 af = *(const half8*)(hrow + kb * 32 + quad * 8);
            #pragma unroll
            for (int nt = 0; nt < 4; ++nt) {
                half8 bf = *(const half8*)(at_sw + ((nt * 8 + kb) * 64 + lane) * 8);
                accm[nt] = __builtin_amdgcn_mfma_f32_16x16x32_f16(af, bf, accm[nt], 0, 0, 0);
            }
        }
        // epilogue: e[m] = sum_n tanh(z[m][n]) * b[n];  D: col=nrow, row=quad*4+r
        #pragma unroll
        for (int r = 0; r < 4; ++r) {
            float p = 0.f;
            #pragma unroll
            for (int nt = 0; nt < 4; ++nt) p += tanhf(accm[nt][r]) * bv[nt];
            p += __shfl_xor(p, 1);
            p += __shfl_xor(p, 2);
            p += __shfl_xor(p, 4);
            p += __shfl_xor(p, 8);
            if (nrow == r) e_l[wave * 16 + quad * 4 + r] = p;
        }
        __syncthreads();

        // ---- wave 0: mask + online-softmax state update ----
        if (wave == 0) {
            long long mi = (long long)b * S_ + c * ROWS_ + tile * 64 + lane;
            int mv = int32enc ? ((const int*)mask)[mi]
                              : (int)((const unsigned char*)mask)[mi];
            float ev = mv ? NEG_ : e_l[lane];
            float mx = ev;
            #pragma unroll
            for (int off = 32; off >= 1; off >>= 1) mx = fmaxf(mx, __shfl_xor(mx, off));
            float m_old = m_s;
            float m_new = fmaxf(m_old, mx);
            float wv_ = __expf(ev - m_new);
            w_l[lane] = wv_;
            float sm = wv_;
            #pragma unroll
            for (int off = 32; off >= 1; off >>= 1) sm += __shfl_xor(sm, off);
            if (lane == 0) {
                float rs = __expf(m_old - m_new);
                l_s = l_s * rs + sm;
                m_s = m_new;
                resc_s = rs;
            }
        }
        __syncthreads();

        // ---- all waves: rescale + accumulate own s-subset (s ≡ wave mod 4) ----
        float rs = resc_s;
        acc0 *= rs; acc1 *= rs; acc2 *= rs; acc3 *= rs;
        #pragma unroll 4
        for (int i = 0; i < 16; ++i) {
            int s = i * 4 + wave;
            float ws = w_l[s];
            union { ushort4 u; _Float16 hh[4]; } pk;
            pk.u = *(const ushort4*)((const unsigned short*)&hf[s * LDH_ + dbase]);
            acc0 = fmaf(ws, (float)pk.hh[0], acc0);
            acc1 = fmaf(ws, (float)pk.hh[1], acc1);
            acc2 = fmaf(ws, (float)pk.hh[2], acc2);
            acc3 = fmaf(ws, (float)pk.hh[3], acc3);
        }
        __syncthreads();   // protects hf/w_l/state before next tile
    }

    // ---- cross-wave reduce + write partial ----
    red[wave * 256 + dbase + 0] = acc0;
    red[wave * 256 + dbase + 1] = acc1;
    red[wave * 256 + dbase + 2] = acc2;
    red[wave * 256 + dbase + 3] = acc3;
    __syncthreads();
    float sum = red[t] + red[256 + t] + red[512 + t] + red[768 + t];
    float* pc = part + (size_t)(b * CHUNKS_ + c) * PSTR_;
    pc[2 + t] = sum;
    if (t == 0) { pc[0] = m_s; pc[1] = l_s; }
}

// Kernel 2: merge per-chunk partials -> out[b][d]
__global__ __launch_bounds__(256) void merge_kernel(
    const float* __restrict__ part, float* __restrict__ out)
{
    const int b = blockIdx.x;
    const int t = threadIdx.x;
    const float* pb = part + (size_t)b * CHUNKS_ * PSTR_;
    float M = NEG_;
    #pragma unroll
    for (int c = 0; c < CHUNKS_; ++c) M = fmaxf(M, pb[c * PSTR_]);
    float L = 0.f, o = 0.f;
    #pragma unroll
    for (int c = 0; c < CHUNKS_; ++c) {
        float sc = __expf(pb[c * PSTR_] - M);
        L += pb[c * PSTR_ + 1] * sc;
        o += pb[c * PSTR_ + 2 + t] * sc;
    }
    out[b * DIM_ + t] = o / L;
}

extern "C" void kernel_launch(void* const* d_in, const int* in_sizes, int n_in,
                              void* d_out, int out_size, void* d_ws, size_t ws_size,
                              hipStream_t stream) {
    const float* h    = (const float*)d_in[0];
    const void*  mask = d_in[1];
    const float* a    = (const float*)d_in[2];
    const float* bvec = (const float*)d_in[3];
    float* out = (float*)d_out;

    char* ws = (char*)d_ws;
    _Float16* at_sw = (_Float16*)ws;              // 32,768 B
    int* flag       = (int*)(ws + 32768);
    float* part     = (float*)(ws + 36864);       // 64*16*258*4 ≈ 1 MiB

    prep_kernel<<<64, 256, 0, stream>>>(a, mask, at_sw, flag);
    fused_kernel<<<B_ * CHUNKS_, 256, 0, stream>>>(h, at_sw, bvec, mask, flag, part);
    merge_kernel<<<B_, 256, 0, stream>>>(part, out);
}